// Round 14
// baseline (204.539 us; speedup 1.0000x reference)
//
#include <hip/hip_runtime.h>
#include <cstdint>
#include <cstddef>

#define NEG_SLOPE 0.2f
// NOTE: packing assumes N < 65536 and node ids < 65536 (N = 50000 here).

typedef __bf16 bf16x8 __attribute__((ext_vector_type(8)));
typedef __bf16 bf16x4 __attribute__((ext_vector_type(4)));
typedef float f32x4 __attribute__((ext_vector_type(4)));

// edge i in [0,NT): real edge for i<E, self-loop (i-E, i-E) otherwise
__device__ __forceinline__ int dstKeyOf(const int* ei, int E, int i) {
  return (i < E) ? ei[E + i] : (i - E);
}
__device__ __forceinline__ int srcKeyOf(const int* ei, int E, int i) {
  return (i < E) ? ei[i] : (i - E);
}

// ---------- merged independent prep: prep_v1 | prep_v2 | W1 transpose | radix hist ----------
__global__ __launch_bounds__(256) void prep_front_kernel(
    const float* __restrict__ W1, const float* __restrict__ as1, const float* __restrict__ ad1,
    const float* __restrict__ W2, const float* __restrict__ as2, const float* __restrict__ ad2,
    const int* __restrict__ ei, int E, int NT, int nblk,
    float* __restrict__ Vs, float* __restrict__ Vd,
    float* __restrict__ vs2, float* __restrict__ vd2,
    __bf16* __restrict__ W1T, int* __restrict__ hist) {
  int bid = blockIdx.x, tid = threadIdx.x;
  if (bid == 0) {
    int k = tid >> 2, h = tid & 3;
    const float* w = W1 + k * 512 + h * 128;
    const float* a1 = as1 + h * 128;
    const float* a2 = ad1 + h * 128;
    float s = 0.f, d = 0.f;
    for (int c = 0; c < 128; ++c) { float wv = w[c]; s += wv * a1[c]; d += wv * a2[c]; }
    Vs[k * 4 + h] = s; Vd[k * 4 + h] = d;
  } else if (bid <= 2) {
    int k = (bid - 1) * 256 + tid;
    if (k < 512) {
      const float* w = W2 + k * 256;
      float s = 0.f, d = 0.f;
      for (int c = 0; c < 256; ++c) { float wv = w[c]; s += wv * as2[c]; d += wv * ad2[c]; }
      vs2[k] = s; vd2[k] = d;
    }
  } else if (bid <= 130) {
    int idx = (bid - 3) * 256 + tid;   // < 32768
    int n = idx >> 6, k = idx & 63;    // W1T[n*64+k] = W1[k*512+n]
    W1T[idx] = (__bf16)W1[(size_t)k * 512 + n];
  } else {
    __shared__ int h[256];
    h[tid] = 0;
    __syncthreads();
    int hblk = bid - 131;
    int sec = hblk >= nblk;
    int blk = hblk - sec * nblk;
    int base = blk * 1024;
#pragma unroll
    for (int j = 0; j < 4; ++j) {
      int i = base + j * 256 + tid;
      if (i < NT) {
        int key = sec ? srcKeyOf(ei, E, i) : dstKeyOf(ei, E, i);
        atomicAdd(&h[key >> 8], 1);   // LDS atomic
      }
    }
    __syncthreads();
    hist[(size_t)(sec * 256 + tid) * nblk + blk] = h[tid];
  }
}

// ---------- fused emb -> bf16 + alpha1 ----------
__global__ void emb_prep_kernel(const float* __restrict__ emb, const float* __restrict__ Vs,
                                const float* __restrict__ Vd, __bf16* __restrict__ embb,
                                float* __restrict__ as_, float* __restrict__ ad_, int n) {
  __shared__ float sVs[256];
  __shared__ float sVd[256];
  for (int i = threadIdx.x; i < 256; i += blockDim.x) { sVs[i] = Vs[i]; sVd[i] = Vd[i]; }
  __syncthreads();
  int node = blockIdx.x * blockDim.x + threadIdx.x;
  if (node >= n) return;
  const float* xr = emb + (size_t)node * 64;
  __bf16* br = embb + (size_t)node * 64;
  float accs[4] = {}, accd[4] = {};
  for (int k = 0; k < 64; k += 4) {
    float4 xv = *(const float4*)(xr + k);
    bf16x4 o;
    o[0] = (__bf16)xv.x; o[1] = (__bf16)xv.y; o[2] = (__bf16)xv.z; o[3] = (__bf16)xv.w;
    *(bf16x4*)(br + k) = o;
#pragma unroll
    for (int h = 0; h < 4; ++h) {
      accs[h] += xv.x * sVs[(k + 0) * 4 + h] + xv.y * sVs[(k + 1) * 4 + h] +
                 xv.z * sVs[(k + 2) * 4 + h] + xv.w * sVs[(k + 3) * 4 + h];
      accd[h] += xv.x * sVd[(k + 0) * 4 + h] + xv.y * sVd[(k + 1) * 4 + h] +
                 xv.z * sVd[(k + 2) * 4 + h] + xv.w * sVd[(k + 3) * 4 + h];
    }
  }
#pragma unroll
  for (int h = 0; h < 4; ++h) {
    as_[(size_t)node * 4 + h] = accs[h];
    ad_[(size_t)node * 4 + h] = accd[h];
  }
}

// ---------- exclusive scan over M ints ----------
__global__ __launch_bounds__(1024) void exscan1_kernel(int* __restrict__ a, int* __restrict__ bsum,
                                                       int M) {
  __shared__ int ws[16];
  int t = threadIdx.x, lane = t & 63, w = t >> 6;
  int i = blockIdx.x * 1024 + t;
  int v = (i < M) ? a[i] : 0;
  int x = v;
#pragma unroll
  for (int s = 1; s < 64; s <<= 1) {
    int tt = __shfl_up(x, s, 64);
    if (lane >= s) x += tt;
  }
  if (lane == 63) ws[w] = x;
  __syncthreads();
  int wo = 0;
  for (int k = 0; k < w; ++k) wo += ws[k];
  if (i < M) a[i] = wo + x - v;
  if (t == 1023) bsum[blockIdx.x] = wo + x;
}

__global__ __launch_bounds__(512) void exscan2_kernel(int* __restrict__ bsum, int nb) {
  __shared__ int buf[512];
  int t = threadIdx.x;
  int v = (t < nb) ? bsum[t] : 0;
  buf[t] = v;
  __syncthreads();
  for (int s = 1; s < 512; s <<= 1) {
    int x = (t >= s) ? buf[t - s] : 0;
    __syncthreads();
    buf[t] += x;
    __syncthreads();
  }
  if (t < nb) bsum[t] = buf[t] - v;
}

__device__ __forceinline__ int scannedAt(const int* hist, const int* bsum, size_t idx) {
  return hist[idx] + bsum[idx >> 10];
}

// ---------- sort pass 1 scatter: high-byte buckets, packed u32 (key<<16 | payload) ----------
__global__ __launch_bounds__(256) void scatter1_kernel(const int* __restrict__ ei, int E, int NT,
                                                       int nblk, const int* __restrict__ hist,
                                                       const int* __restrict__ bsum,
                                                       unsigned* __restrict__ p1buf) {
  __shared__ int bins[256];
  int tid = threadIdx.x;
  int sec = (int)blockIdx.x >= nblk;
  int blk = blockIdx.x - sec * nblk;
  bins[tid] = scannedAt(hist, bsum, (size_t)(sec * 256 + tid) * nblk + blk);
  __syncthreads();
  int base = blk * 1024;
#pragma unroll
  for (int j = 0; j < 4; ++j) {
    int i = base + j * 256 + tid;
    if (i < NT) {
      int k, p;
      if (sec == 0) { k = dstKeyOf(ei, E, i); p = srcKeyOf(ei, E, i); }
      else          { k = srcKeyOf(ei, E, i); p = dstKeyOf(ei, E, i); }
      int pos = atomicAdd(&bins[k >> 8], 1);   // LDS atomic
      p1buf[pos] = ((unsigned)k << 16) | (unsigned)p;
    }
  }
}

// ---------- sort pass 2: per-bucket low-byte sort in LDS (packed) ----------
__global__ __launch_bounds__(1024) void sortlow_kernel(const int* __restrict__ hist,
                                                       const int* __restrict__ bsum,
                                                       const unsigned* __restrict__ p1buf,
                                                       int nblk, int NT,
                                                       unsigned* __restrict__ pkD,
                                                       unsigned* __restrict__ pkS) {
  __shared__ int h[256];
  __shared__ int b2[256];
  int tid = threadIdx.x;
  int w = blockIdx.x;
  int sec = w >= 256;
  int d0 = w - sec * 256;
  int beg = scannedAt(hist, bsum, (size_t)(sec * 256 + d0) * nblk);
  int end = (w == 511) ? 2 * NT : scannedAt(hist, bsum, (size_t)(sec * 256 + d0 + 1) * nblk);
  if (tid < 256) h[tid] = 0;
  __syncthreads();
  for (int i = beg + tid; i < end; i += 1024) atomicAdd(&h[(p1buf[i] >> 16) & 255], 1);
  __syncthreads();
  if (tid < 256) b2[tid] = h[tid];
  __syncthreads();
  for (int s = 1; s < 256; s <<= 1) {
    int x = (tid >= s && tid < 256) ? b2[tid - s] : 0;
    __syncthreads();
    if (tid < 256) b2[tid] += x;
    __syncthreads();
  }
  if (tid < 256) b2[tid] = beg + b2[tid] - h[tid];
  __syncthreads();
  for (int i = beg + tid; i < end; i += 1024) {
    unsigned pk = p1buf[i];
    int pos = atomicAdd(&b2[(pk >> 16) & 255], 1);   // LDS atomic; unstable = fine
    if (sec == 0) pkD[pos] = pk;
    else          pkS[pos - NT] = pk;
  }
}

// ---------- post-sort: layer-1 edge weights (dst-order) | segment bounds ----------
__global__ __launch_bounds__(256) void post_sort_kernel(
    const unsigned* __restrict__ pkD, const unsigned* __restrict__ pkS,
    const float* __restrict__ as1, const float* __restrict__ ad1,
    float4* __restrict__ ew4, int* __restrict__ off, int* __restrict__ offS,
    int NT, int n, int ewBlocks) {
  if ((int)blockIdx.x < ewBlocks) {
    int i = blockIdx.x * 256 + threadIdx.x;
    if (i >= NT) return;
    unsigned pk = pkD[i];
    int s = pk & 0xFFFF, d = pk >> 16;
    float4 a = *(const float4*)(as1 + (size_t)s * 4);
    float4 b = *(const float4*)(ad1 + (size_t)d * 4);
    float l0 = a.x + b.x; l0 = l0 >= 0.f ? l0 : NEG_SLOPE * l0;
    float l1 = a.y + b.y; l1 = l1 >= 0.f ? l1 : NEG_SLOPE * l1;
    float l2 = a.z + b.z; l2 = l2 >= 0.f ? l2 : NEG_SLOPE * l2;
    float l3 = a.w + b.w; l3 = l3 >= 0.f ? l3 : NEG_SLOPE * l3;
    ew4[i] = make_float4(__expf(l0), __expf(l1), __expf(l2), __expf(l3));
  } else {
    int x = (blockIdx.x - ewBlocks) * 256 + threadIdx.x;
    if (x == 0) { off[n] = NT; offS[n] = NT; }
    if (x >= 2 * n) return;
    int sec = x >= n;
    int d = x - sec * n;
    const unsigned* key = sec ? pkS : pkD;
    unsigned target = (unsigned)d << 16;
    int lo = 0, hi = NT;
    while (lo < hi) {
      int mid = (lo + hi) >> 1;
      if (key[mid] < target) lo = mid + 1; else hi = mid;
    }
    if (sec) offS[d] = lo; else off[d] = lo;
  }
}

// ---------- layer-1 aggregation in EMBEDDING space ----------
// 4 groups x 16 lanes, 4 edges per group in flight (16 gather chains/wave); FMA-only body
__global__ __launch_bounds__(128) void agg_emb_kernel(
    const int* __restrict__ off, const unsigned* __restrict__ pkD,
    const float4* __restrict__ ew4, const __bf16* __restrict__ embb,
    __bf16* __restrict__ aggE) {
  int d = blockIdx.x * 2 + (threadIdx.x >> 6);
  int lane = threadIdx.x & 63;
  int g = lane >> 4, p = lane & 15;
  float acc[4][4] = {};   // [head][chan]
  float wsum[4] = {};
  int beg = off[d], end = off[d + 1];
  for (int i0 = beg; i0 < end; i0 += 16) {
#pragma unroll
    for (int q = 0; q < 4; ++q) {
      int i = i0 + q * 4 + g;
      int idx = (i < end) ? i : (end - 1);
      float vm = (i < end) ? 1.f : 0.f;
      unsigned pk = pkD[idx];
      int s = pk & 0xFFFF;
      float4 wv = ew4[idx];
      bf16x4 v = *(const bf16x4*)(embb + (size_t)s * 64 + p * 4);
      float w0 = wv.x * vm, w1 = wv.y * vm, w2 = wv.z * vm, w3 = wv.w * vm;
      float f0 = (float)v[0], f1 = (float)v[1], f2 = (float)v[2], f3 = (float)v[3];
      acc[0][0] += w0 * f0; acc[0][1] += w0 * f1; acc[0][2] += w0 * f2; acc[0][3] += w0 * f3;
      acc[1][0] += w1 * f0; acc[1][1] += w1 * f1; acc[1][2] += w1 * f2; acc[1][3] += w1 * f3;
      acc[2][0] += w2 * f0; acc[2][1] += w2 * f1; acc[2][2] += w2 * f2; acc[2][3] += w2 * f3;
      acc[3][0] += w3 * f0; acc[3][1] += w3 * f1; acc[3][2] += w3 * f2; acc[3][3] += w3 * f3;
      wsum[0] += w0; wsum[1] += w1; wsum[2] += w2; wsum[3] += w3;
    }
  }
#pragma unroll
  for (int h = 0; h < 4; ++h) {
#pragma unroll
    for (int c = 0; c < 4; ++c) {
      acc[h][c] += __shfl_xor(acc[h][c], 16, 64);
      acc[h][c] += __shfl_xor(acc[h][c], 32, 64);
    }
    wsum[h] += __shfl_xor(wsum[h], 16, 64);
    wsum[h] += __shfl_xor(wsum[h], 32, 64);
  }
  if (g == 0) {
#pragma unroll
    for (int h = 0; h < 4; ++h) {
      float inv = 1.0f / wsum[h];
      bf16x4 o;
      o[0] = (__bf16)(acc[h][0] * inv); o[1] = (__bf16)(acc[h][1] * inv);
      o[2] = (__bf16)(acc[h][2] * inv); o[3] = (__bf16)(acc[h][3] * inv);
      *(bf16x4*)(aggE + (size_t)d * 256 + h * 64 + p * 4) = o;
    }
  }
}

// ---------- reconstruct x1 (per-head MFMA GEMM + bias + ELU) with fused alpha2 partials ----------
__global__ __launch_bounds__(256) void gemm1p_kernel(const __bf16* __restrict__ aggE,
                                                     const __bf16* __restrict__ W1T,
                                                     const float* __restrict__ b1,
                                                     const float* __restrict__ vs2,
                                                     const float* __restrict__ vd2,
                                                     __bf16* __restrict__ x1,
                                                     float* __restrict__ as2p,
                                                     float* __restrict__ ad2p, int M) {
  __shared__ __bf16 Asl[128 * 72];
  __shared__ __bf16 Bsl[128 * 72];
  int tid = threadIdx.x;
  int h = blockIdx.z;
  int m0 = blockIdx.x * 128;
  int wave = tid >> 6, lane = tid & 63;
  int wm = (wave >> 1) * 64, wn = (wave & 1) * 64;
  int l15 = lane & 15, kg = lane >> 4;
#pragma unroll
  for (int i = 0; i < 4; ++i) {
    int c = tid + i * 256;
    int row = c >> 3, off = (c & 7) * 8;
    bf16x8 va = {};
    int gr = m0 + row;
    if (gr < M) va = *(const bf16x8*)(aggE + (size_t)gr * 256 + h * 64 + off);
    *(bf16x8*)(&Asl[row * 72 + off]) = va;
    bf16x8 vb = *(const bf16x8*)(W1T + ((size_t)h * 128 + row) * 64 + off);
    *(bf16x8*)(&Bsl[row * 72 + off]) = vb;
  }
  __syncthreads();
  f32x4 acc[4][4] = {};
#pragma unroll
  for (int ks = 0; ks < 2; ++ks) {
    bf16x8 af[4], bfr[4];
#pragma unroll
    for (int f = 0; f < 4; ++f) {
      af[f]  = *(const bf16x8*)(&Asl[(wm + f * 16 + l15) * 72 + kg * 8 + ks * 32]);
      bfr[f] = *(const bf16x8*)(&Bsl[(wn + f * 16 + l15) * 72 + kg * 8 + ks * 32]);
    }
#pragma unroll
    for (int i = 0; i < 4; ++i)
#pragma unroll
      for (int j = 0; j < 4; ++j)
        acc[i][j] = __builtin_amdgcn_mfma_f32_16x16x32_bf16(af[i], bfr[j], acc[i][j], 0, 0, 0);
  }
  float bv[4], vsv[4], vdv[4];
#pragma unroll
  for (int j = 0; j < 4; ++j) {
    int col = h * 128 + wn + j * 16 + l15;
    bv[j] = b1[col]; vsv[j] = vs2[col]; vdv[j] = vd2[col];
  }
  int slab = h * 2 + (wn >> 6);
#pragma unroll
  for (int i = 0; i < 4; ++i)
#pragma unroll
    for (int r = 0; r < 4; ++r) {
      int lrow = wm + i * 16 + kg * 4 + r;
      int row = m0 + lrow;
      bool vrow = row < M;
      float ps = 0.f, pd = 0.f;
#pragma unroll
      for (int j = 0; j < 4; ++j) {
        float a = acc[i][j][r] + bv[j];
        a = a > 0.f ? a : __expf(a) - 1.f;   // ELU
        __bf16 xb = (__bf16)a;
        if (vrow) x1[(size_t)row * 512 + h * 128 + wn + j * 16 + l15] = xb;
        float af = (float)xb;
        ps += af * vsv[j];
        pd += af * vdv[j];
      }
      ps += __shfl_xor(ps, 1, 16); ps += __shfl_xor(ps, 2, 16);
      ps += __shfl_xor(ps, 4, 16); ps += __shfl_xor(ps, 8, 16);
      pd += __shfl_xor(pd, 1, 16); pd += __shfl_xor(pd, 2, 16);
      pd += __shfl_xor(pd, 4, 16); pd += __shfl_xor(pd, 8, 16);
      if (l15 == 0 && vrow) {
        as2p[(size_t)slab * M + row] = ps;
        ad2p[(size_t)slab * M + row] = pd;
      }
    }
}

// ---------- merge alpha2 partial slabs ----------
__global__ void merge_alpha2_kernel(const float* __restrict__ as2p, const float* __restrict__ ad2p,
                                    float* __restrict__ as2, float* __restrict__ ad2, int n) {
  int i = blockIdx.x * blockDim.x + threadIdx.x;
  if (i >= n) return;
  float s = 0.f, d = 0.f;
#pragma unroll
  for (int b = 0; b < 8; ++b) {
    s += as2p[(size_t)b * n + i];
    d += ad2p[(size_t)b * n + i];
  }
  as2[i] = s; ad2[i] = d;
}

// ---------- layer-2 denom: advw[d] = {ad2[d], invN / sum_e w_e} ----------
__global__ __launch_bounds__(256) void invw_kernel(
    const int* __restrict__ off, const unsigned* __restrict__ pkD,
    const float* __restrict__ as2, const float* __restrict__ ad2,
    float2* __restrict__ advw, float invN, int n) {
  int d = (blockIdx.x * 256 + threadIdx.x) >> 4;
  int p = threadIdx.x & 15;
  if (d >= n) return;
  float adv = ad2[d];
  int beg = off[d], end = off[d + 1];
  float wsum = 0.f;
  for (int i = beg + p; i < end; i += 16) {
    float l = as2[pkD[i] & 0xFFFF] + adv;
    l = l >= 0.f ? l : NEG_SLOPE * l;
    wsum += __expf(l);
  }
  wsum += __shfl_xor(wsum, 1, 16); wsum += __shfl_xor(wsum, 2, 16);
  wsum += __shfl_xor(wsum, 4, 16); wsum += __shfl_xor(wsum, 8, 16);
  if (p == 0) advw[d] = make_float2(adv, invN / wsum);
}

// ---------- gamma via CSC walk (no atomics) ----------
__global__ __launch_bounds__(256) void gamma_csc_kernel(
    const int* __restrict__ offS, const unsigned* __restrict__ pkS,
    const float* __restrict__ as2, const float2* __restrict__ advw,
    float* __restrict__ gamma, int n) {
  int s = (blockIdx.x * 256 + threadIdx.x) >> 4;
  int p = threadIdx.x & 15;
  if (s >= n) return;
  float as2s = as2[s];
  int beg = offS[s], end = offS[s + 1];
  float gsum = 0.f;
  for (int i = beg + p; i < end; i += 16) {
    float2 av = advw[pkS[i] & 0xFFFF];
    float l = as2s + av.x;
    l = l >= 0.f ? l : NEG_SLOPE * l;
    gsum += __expf(l) * av.y;
  }
  gsum += __shfl_xor(gsum, 1, 16); gsum += __shfl_xor(gsum, 2, 16);
  gsum += __shfl_xor(gsum, 4, 16); gsum += __shfl_xor(gsum, 8, 16);
  if (p == 0) gamma[s] = gsum;
}

// ---------- weighted column sum stage 1 ----------
__global__ __launch_bounds__(256) void colsum1_kernel(const __bf16* __restrict__ x1,
                                                      const float* __restrict__ gamma,
                                                      float* __restrict__ pcol, int n) {
  __shared__ float sc[512];
  int t = threadIdx.x;
  sc[t] = 0.f; sc[t + 256] = 0.f;
  __syncthreads();
  int lane = t & 63, w = t >> 6;
  float acc[8] = {};
  for (int r = blockIdx.x * 4 + w; r < n; r += gridDim.x * 4) {
    float g = gamma[r];
    bf16x8 v = *(const bf16x8*)(x1 + (size_t)r * 512 + lane * 8);
#pragma unroll
    for (int j = 0; j < 8; ++j) acc[j] += g * (float)v[j];
  }
#pragma unroll
  for (int j = 0; j < 8; ++j) atomicAdd(&sc[lane * 8 + j], acc[j]);
  __syncthreads();
  pcol[(size_t)blockIdx.x * 512 + t] = sc[t];
  pcol[(size_t)blockIdx.x * 512 + 256 + t] = sc[t + 256];
}

// stage 2: parallel block-sliced reduction
__global__ __launch_bounds__(256) void colsum2_kernel(const float* __restrict__ pcol,
                                                      float* __restrict__ colsum, int nb) {
  int c = threadIdx.x;
  int b0 = blockIdx.x * 16;
  float a0 = 0.f, a1 = 0.f;
#pragma unroll 4
  for (int b = b0; b < b0 + 16; ++b) {
    if (b < nb) {
      a0 += pcol[(size_t)b * 512 + c];
      a1 += pcol[(size_t)b * 512 + 256 + c];
    }
  }
  atomicAdd(&colsum[c], a0);
  atomicAdd(&colsum[c + 256], a1);
}

// ---------- final matvec: out[c] = colsum . W2[:,c] + b2[c] ----------
__global__ void final_kernel(const float* __restrict__ colsum, const float* __restrict__ W2,
                             const float* __restrict__ b2, float* __restrict__ out) {
  int c = threadIdx.x;  // 256
  int k0 = blockIdx.x * 64;  // 8 blocks x 64 k
  float acc = 0.f;
  for (int k = k0; k < k0 + 64; ++k) acc += colsum[k] * W2[(size_t)k * 256 + c];
  if (blockIdx.x == 0) acc += b2[c];
  atomicAdd(&out[c], acc);
}

__global__ void bcast_kernel(float* __restrict__ dout, int total) {
  int i = blockIdx.x * blockDim.x + threadIdx.x;
  if (i >= 256 && i < total) dout[i] = dout[i & 255];
}

// ---------- host ----------
extern "C" void kernel_launch(void* const* d_in, const int* in_sizes, int n_in,
                              void* d_out, int out_size, void* d_ws, size_t ws_size,
                              hipStream_t stream) {
  const int* ei = (const int*)d_in[0];
  const float* emb = (const float*)d_in[1];
  const float* W1 = (const float*)d_in[2];
  const float* as1w = (const float*)d_in[3];
  const float* ad1w = (const float*)d_in[4];
  const float* b1 = (const float*)d_in[5];
  const float* W2 = (const float*)d_in[6];
  const float* as2w = (const float*)d_in[7];
  const float* ad2w = (const float*)d_in[8];
  const float* b2 = (const float*)d_in[9];
  float* out = (float*)d_out;

  const int E = in_sizes[0] / 2;
  const int N = in_sizes[1] / 64;
  const int NT = E + N;
  const int CS1 = 1024;                 // colsum stage-1 blocks
  const int nblk = (NT + 1023) / 1024;  // sort blocks per section
  const int M = 2 * 256 * nblk;         // hist size
  const int scanBlocks = (M + 1023) / 1024;

  char* ws = (char*)d_ws;
  size_t o = 0;
  auto alloc = [&](size_t bytes) { size_t r = o; o += (bytes + 255) & ~(size_t)255; return r; };
  __bf16* embb  = (__bf16*)(ws + alloc((size_t)N * 64 * 2));
  __bf16* aggE  = (__bf16*)(ws + alloc((size_t)N * 256 * 2));
  __bf16* x1    = (__bf16*)(ws + alloc((size_t)N * 512 * 2));
  __bf16* W1T   = (__bf16*)(ws + alloc((size_t)512 * 64 * 2));
  float* as1    = (float*)(ws + alloc((size_t)N * 4 * 4));
  float* ad1    = (float*)(ws + alloc((size_t)N * 4 * 4));
  float* as2    = (float*)(ws + alloc((size_t)N * 4));
  float* ad2    = (float*)(ws + alloc((size_t)N * 4));
  float* as2p   = (float*)(ws + alloc((size_t)8 * N * 4));
  float* ad2p   = (float*)(ws + alloc((size_t)8 * N * 4));
  float* pcol   = (float*)(ws + alloc((size_t)CS1 * 512 * 4));
  float2* advw  = (float2*)(ws + alloc((size_t)N * 8));
  float* gamma  = (float*)(ws + alloc((size_t)N * 4));
  int* off      = (int*)(ws + alloc((size_t)(N + 1) * 4));
  int* offS     = (int*)(ws + alloc((size_t)(N + 1) * 4));
  unsigned* pkD = (unsigned*)(ws + alloc((size_t)NT * 4));  // (dst<<16)|src, dst-sorted
  unsigned* pkS = (unsigned*)(ws + alloc((size_t)NT * 4));  // (src<<16)|dst, src-sorted
  unsigned* p1buf = (unsigned*)(ws + alloc((size_t)2 * NT * 4));
  int* hist     = (int*)(ws + alloc((size_t)M * 4));
  int* bsum     = (int*)(ws + alloc(512 * 4));
  float4* ew4   = (float4*)(ws + alloc((size_t)NT * 16));
  size_t zbeg = o;
  float* colsum = (float*)(ws + alloc(512 * 4));
  size_t zend = o;
  float* Vs1    = (float*)(ws + alloc(64 * 4 * 4));
  float* Vd1    = (float*)(ws + alloc(64 * 4 * 4));
  float* vs2    = (float*)(ws + alloc(512 * 4));
  float* vd2    = (float*)(ws + alloc(512 * 4));

  hipMemsetAsync(ws + zbeg, 0, zend - zbeg, stream);
  hipMemsetAsync(d_out, 0, (size_t)out_size * 4, stream);

  // merged prep (weights) + radix histogram
  prep_front_kernel<<<131 + 2 * nblk, 256, 0, stream>>>(W1, as1w, ad1w, W2, as2w, ad2w,
                                                        ei, E, NT, nblk,
                                                        Vs1, Vd1, vs2, vd2, W1T, hist);
  int nb = (N + 255) / 256;
  emb_prep_kernel<<<nb, 256, 0, stream>>>(emb, Vs1, Vd1, embb, as1, ad1, N);

  // atomic-free CSR (by dst) + CSC (by src) via MSD radix sort, packed u32
  exscan1_kernel<<<scanBlocks, 1024, 0, stream>>>(hist, bsum, M);
  exscan2_kernel<<<1, 512, 0, stream>>>(bsum, scanBlocks);
  scatter1_kernel<<<2 * nblk, 256, 0, stream>>>(ei, E, NT, nblk, hist, bsum, p1buf);
  sortlow_kernel<<<512, 1024, 0, stream>>>(hist, bsum, p1buf, nblk, NT, pkD, pkS);

  // edge weights (layer 1) + segment bounds, one dispatch
  int ewBlocks = (NT + 255) / 256;
  int bBlocks = (2 * N + 255) / 256;
  post_sort_kernel<<<ewBlocks + bBlocks, 256, 0, stream>>>(pkD, pkS, as1, ad1,
                                                           ew4, off, offS, NT, N, ewBlocks);

  // layer 1
  agg_emb_kernel<<<N / 2, 128, 0, stream>>>(off, pkD, ew4, embb, aggE);
  dim3 g1((N + 127) / 128, 1, 4);
  gemm1p_kernel<<<g1, 256, 0, stream>>>(aggE, W1T, b1, vs2, vd2, x1, as2p, ad2p, N);
  merge_alpha2_kernel<<<nb, 256, 0, stream>>>(as2p, ad2p, as2, ad2, N);

  // layer 2 collapsed
  invw_kernel<<<(N * 16 + 255) / 256, 256, 0, stream>>>(off, pkD, as2, ad2, advw,
                                                        1.0f / (float)N, N);
  gamma_csc_kernel<<<(N * 16 + 255) / 256, 256, 0, stream>>>(offS, pkS, as2, advw, gamma, N);
  colsum1_kernel<<<CS1, 256, 0, stream>>>(x1, gamma, pcol, N);
  colsum2_kernel<<<CS1 / 16, 256, 0, stream>>>(pcol, colsum, CS1);
  final_kernel<<<8, 256, 0, stream>>>(colsum, W2, b2, out);

  if (out_size > 256) {
    bcast_kernel<<<(out_size + 255) / 256, 256, 0, stream>>>(out, out_size);
  }
}

// Round 15
// 188.751 us; speedup vs baseline: 1.0836x; 1.0836x over previous
//
#include <hip/hip_runtime.h>
#include <cstdint>
#include <cstddef>

#define NEG_SLOPE 0.2f
// NOTE: packing assumes N < 65536 and node ids < 65536 (N = 50000 here).

typedef __bf16 bf16x8 __attribute__((ext_vector_type(8)));
typedef __bf16 bf16x4 __attribute__((ext_vector_type(4)));
typedef float f32x4 __attribute__((ext_vector_type(4)));

// edge i in [0,NT): real edge for i<E, self-loop (i-E, i-E) otherwise
__device__ __forceinline__ int dstKeyOf(const int* ei, int E, int i) {
  return (i < E) ? ei[E + i] : (i - E);
}
__device__ __forceinline__ int srcKeyOf(const int* ei, int E, int i) {
  return (i < E) ? ei[i] : (i - E);
}

// ---------- merged independent prep: prep_v1 | prep_v2 | W1 transpose | radix hist ----------
__global__ __launch_bounds__(256) void prep_front_kernel(
    const float* __restrict__ W1, const float* __restrict__ as1, const float* __restrict__ ad1,
    const float* __restrict__ W2, const float* __restrict__ as2, const float* __restrict__ ad2,
    const int* __restrict__ ei, int E, int NT, int nblk,
    float* __restrict__ Vs, float* __restrict__ Vd,
    float* __restrict__ vs2, float* __restrict__ vd2,
    __bf16* __restrict__ W1T, int* __restrict__ hist) {
  int bid = blockIdx.x, tid = threadIdx.x;
  if (bid == 0) {
    int k = tid >> 2, h = tid & 3;
    const float* w = W1 + k * 512 + h * 128;
    const float* a1 = as1 + h * 128;
    const float* a2 = ad1 + h * 128;
    float s = 0.f, d = 0.f;
    for (int c = 0; c < 128; ++c) { float wv = w[c]; s += wv * a1[c]; d += wv * a2[c]; }
    Vs[k * 4 + h] = s; Vd[k * 4 + h] = d;
  } else if (bid <= 2) {
    int k = (bid - 1) * 256 + tid;
    if (k < 512) {
      const float* w = W2 + k * 256;
      float s = 0.f, d = 0.f;
      for (int c = 0; c < 256; ++c) { float wv = w[c]; s += wv * as2[c]; d += wv * ad2[c]; }
      vs2[k] = s; vd2[k] = d;
    }
  } else if (bid <= 130) {
    int idx = (bid - 3) * 256 + tid;   // < 32768
    int n = idx >> 6, k = idx & 63;    // W1T[n*64+k] = W1[k*512+n]
    W1T[idx] = (__bf16)W1[(size_t)k * 512 + n];
  } else {
    __shared__ int h[256];
    h[tid] = 0;
    __syncthreads();
    int hblk = bid - 131;
    int sec = hblk >= nblk;
    int blk = hblk - sec * nblk;
    int base = blk * 1024;
#pragma unroll
    for (int j = 0; j < 4; ++j) {
      int i = base + j * 256 + tid;
      if (i < NT) {
        int key = sec ? srcKeyOf(ei, E, i) : dstKeyOf(ei, E, i);
        atomicAdd(&h[key >> 8], 1);   // LDS atomic
      }
    }
    __syncthreads();
    hist[(size_t)(sec * 256 + tid) * nblk + blk] = h[tid];
  }
}

// ---------- fused emb -> bf16 + alpha1 ----------
__global__ void emb_prep_kernel(const float* __restrict__ emb, const float* __restrict__ Vs,
                                const float* __restrict__ Vd, __bf16* __restrict__ embb,
                                float* __restrict__ as_, float* __restrict__ ad_, int n) {
  __shared__ float sVs[256];
  __shared__ float sVd[256];
  for (int i = threadIdx.x; i < 256; i += blockDim.x) { sVs[i] = Vs[i]; sVd[i] = Vd[i]; }
  __syncthreads();
  int node = blockIdx.x * blockDim.x + threadIdx.x;
  if (node >= n) return;
  const float* xr = emb + (size_t)node * 64;
  __bf16* br = embb + (size_t)node * 64;
  float accs[4] = {}, accd[4] = {};
  for (int k = 0; k < 64; k += 4) {
    float4 xv = *(const float4*)(xr + k);
    bf16x4 o;
    o[0] = (__bf16)xv.x; o[1] = (__bf16)xv.y; o[2] = (__bf16)xv.z; o[3] = (__bf16)xv.w;
    *(bf16x4*)(br + k) = o;
#pragma unroll
    for (int h = 0; h < 4; ++h) {
      accs[h] += xv.x * sVs[(k + 0) * 4 + h] + xv.y * sVs[(k + 1) * 4 + h] +
                 xv.z * sVs[(k + 2) * 4 + h] + xv.w * sVs[(k + 3) * 4 + h];
      accd[h] += xv.x * sVd[(k + 0) * 4 + h] + xv.y * sVd[(k + 1) * 4 + h] +
                 xv.z * sVd[(k + 2) * 4 + h] + xv.w * sVd[(k + 3) * 4 + h];
    }
  }
#pragma unroll
  for (int h = 0; h < 4; ++h) {
    as_[(size_t)node * 4 + h] = accs[h];
    ad_[(size_t)node * 4 + h] = accd[h];
  }
}

// ---------- exclusive scan over M ints ----------
__global__ __launch_bounds__(1024) void exscan1_kernel(int* __restrict__ a, int* __restrict__ bsum,
                                                       int M) {
  __shared__ int ws[16];
  int t = threadIdx.x, lane = t & 63, w = t >> 6;
  int i = blockIdx.x * 1024 + t;
  int v = (i < M) ? a[i] : 0;
  int x = v;
#pragma unroll
  for (int s = 1; s < 64; s <<= 1) {
    int tt = __shfl_up(x, s, 64);
    if (lane >= s) x += tt;
  }
  if (lane == 63) ws[w] = x;
  __syncthreads();
  int wo = 0;
  for (int k = 0; k < w; ++k) wo += ws[k];
  if (i < M) a[i] = wo + x - v;
  if (t == 1023) bsum[blockIdx.x] = wo + x;
}

__global__ __launch_bounds__(512) void exscan2_kernel(int* __restrict__ bsum, int nb) {
  __shared__ int buf[512];
  int t = threadIdx.x;
  int v = (t < nb) ? bsum[t] : 0;
  buf[t] = v;
  __syncthreads();
  for (int s = 1; s < 512; s <<= 1) {
    int x = (t >= s) ? buf[t - s] : 0;
    __syncthreads();
    buf[t] += x;
    __syncthreads();
  }
  if (t < nb) bsum[t] = buf[t] - v;
}

__device__ __forceinline__ int scannedAt(const int* hist, const int* bsum, size_t idx) {
  return hist[idx] + bsum[idx >> 10];
}

// ---------- sort pass 1 scatter: high-byte buckets, packed u32 (key<<16 | payload) ----------
__global__ __launch_bounds__(256) void scatter1_kernel(const int* __restrict__ ei, int E, int NT,
                                                       int nblk, const int* __restrict__ hist,
                                                       const int* __restrict__ bsum,
                                                       unsigned* __restrict__ p1buf) {
  __shared__ int bins[256];
  int tid = threadIdx.x;
  int sec = (int)blockIdx.x >= nblk;
  int blk = blockIdx.x - sec * nblk;
  bins[tid] = scannedAt(hist, bsum, (size_t)(sec * 256 + tid) * nblk + blk);
  __syncthreads();
  int base = blk * 1024;
#pragma unroll
  for (int j = 0; j < 4; ++j) {
    int i = base + j * 256 + tid;
    if (i < NT) {
      int k, p;
      if (sec == 0) { k = dstKeyOf(ei, E, i); p = srcKeyOf(ei, E, i); }
      else          { k = srcKeyOf(ei, E, i); p = dstKeyOf(ei, E, i); }
      int pos = atomicAdd(&bins[k >> 8], 1);   // LDS atomic
      p1buf[pos] = ((unsigned)k << 16) | (unsigned)p;
    }
  }
}

// ---------- sort pass 2: per-bucket low-byte sort in LDS (packed) ----------
__global__ __launch_bounds__(1024) void sortlow_kernel(const int* __restrict__ hist,
                                                       const int* __restrict__ bsum,
                                                       const unsigned* __restrict__ p1buf,
                                                       int nblk, int NT,
                                                       unsigned* __restrict__ pkD,
                                                       unsigned* __restrict__ pkS) {
  __shared__ int h[256];
  __shared__ int b2[256];
  int tid = threadIdx.x;
  int w = blockIdx.x;
  int sec = w >= 256;
  int d0 = w - sec * 256;
  int beg = scannedAt(hist, bsum, (size_t)(sec * 256 + d0) * nblk);
  int end = (w == 511) ? 2 * NT : scannedAt(hist, bsum, (size_t)(sec * 256 + d0 + 1) * nblk);
  if (tid < 256) h[tid] = 0;
  __syncthreads();
  for (int i = beg + tid; i < end; i += 1024) atomicAdd(&h[(p1buf[i] >> 16) & 255], 1);
  __syncthreads();
  if (tid < 256) b2[tid] = h[tid];
  __syncthreads();
  for (int s = 1; s < 256; s <<= 1) {
    int x = (tid >= s && tid < 256) ? b2[tid - s] : 0;
    __syncthreads();
    if (tid < 256) b2[tid] += x;
    __syncthreads();
  }
  if (tid < 256) b2[tid] = beg + b2[tid] - h[tid];
  __syncthreads();
  for (int i = beg + tid; i < end; i += 1024) {
    unsigned pk = p1buf[i];
    int pos = atomicAdd(&b2[(pk >> 16) & 255], 1);   // LDS atomic; unstable = fine
    if (sec == 0) pkD[pos] = pk;
    else          pkS[pos - NT] = pk;
  }
}

// ---------- post-sort: layer-1 edge weights (dst-order) | segment bounds ----------
__global__ __launch_bounds__(256) void post_sort_kernel(
    const unsigned* __restrict__ pkD, const unsigned* __restrict__ pkS,
    const float* __restrict__ as1, const float* __restrict__ ad1,
    float4* __restrict__ ew4, int* __restrict__ off, int* __restrict__ offS,
    int NT, int n, int ewBlocks) {
  if ((int)blockIdx.x < ewBlocks) {
    int i = blockIdx.x * 256 + threadIdx.x;
    if (i >= NT) return;
    unsigned pk = pkD[i];
    int s = pk & 0xFFFF, d = pk >> 16;
    float4 a = *(const float4*)(as1 + (size_t)s * 4);
    float4 b = *(const float4*)(ad1 + (size_t)d * 4);
    float l0 = a.x + b.x; l0 = l0 >= 0.f ? l0 : NEG_SLOPE * l0;
    float l1 = a.y + b.y; l1 = l1 >= 0.f ? l1 : NEG_SLOPE * l1;
    float l2 = a.z + b.z; l2 = l2 >= 0.f ? l2 : NEG_SLOPE * l2;
    float l3 = a.w + b.w; l3 = l3 >= 0.f ? l3 : NEG_SLOPE * l3;
    ew4[i] = make_float4(__expf(l0), __expf(l1), __expf(l2), __expf(l3));
  } else {
    int x = (blockIdx.x - ewBlocks) * 256 + threadIdx.x;
    if (x == 0) { off[n] = NT; offS[n] = NT; }
    if (x >= 2 * n) return;
    int sec = x >= n;
    int d = x - sec * n;
    const unsigned* key = sec ? pkS : pkD;
    unsigned target = (unsigned)d << 16;
    int lo = 0, hi = NT;
    while (lo < hi) {
      int mid = (lo + hi) >> 1;
      if (key[mid] < target) lo = mid + 1; else hi = mid;
    }
    if (sec) offS[d] = lo; else off[d] = lo;
  }
}

// ---------- layer-1 aggregation in EMBEDDING space ----------
// 4 groups x 16 lanes, 2-edge unroll (step 8): 8 gather chains/wave, cheap 40-shuffle epilogue
__global__ __launch_bounds__(128) void agg_emb_kernel(
    const int* __restrict__ off, const unsigned* __restrict__ pkD,
    const float4* __restrict__ ew4, const __bf16* __restrict__ embb,
    __bf16* __restrict__ aggE) {
  int d = blockIdx.x * 2 + (threadIdx.x >> 6);
  int lane = threadIdx.x & 63;
  int g = lane >> 4, p = lane & 15;
  float acc[4][4] = {};   // [head][chan]
  float wsum[4] = {};
  int beg = off[d], end = off[d + 1];
  for (int i0 = beg; i0 < end; i0 += 8) {
    int iA = i0 + g, iB = i0 + 4 + g;
    int idxA = (iA < end) ? iA : (end - 1);
    int idxB = (iB < end) ? iB : (end - 1);
    float vmA = (iA < end) ? 1.f : 0.f;
    float vmB = (iB < end) ? 1.f : 0.f;
    int sA = pkD[idxA] & 0xFFFF;
    int sB = pkD[idxB] & 0xFFFF;
    float4 wAv = ew4[idxA];
    float4 wBv = ew4[idxB];
    bf16x4 vA = *(const bf16x4*)(embb + (size_t)sA * 64 + p * 4);
    bf16x4 vB = *(const bf16x4*)(embb + (size_t)sB * 64 + p * 4);
    float wA0 = wAv.x * vmA, wA1 = wAv.y * vmA, wA2 = wAv.z * vmA, wA3 = wAv.w * vmA;
    float wB0 = wBv.x * vmB, wB1 = wBv.y * vmB, wB2 = wBv.z * vmB, wB3 = wBv.w * vmB;
    float fA0 = (float)vA[0], fA1 = (float)vA[1], fA2 = (float)vA[2], fA3 = (float)vA[3];
    float fB0 = (float)vB[0], fB1 = (float)vB[1], fB2 = (float)vB[2], fB3 = (float)vB[3];
    acc[0][0] += wA0 * fA0; acc[0][1] += wA0 * fA1; acc[0][2] += wA0 * fA2; acc[0][3] += wA0 * fA3;
    acc[1][0] += wA1 * fA0; acc[1][1] += wA1 * fA1; acc[1][2] += wA1 * fA2; acc[1][3] += wA1 * fA3;
    acc[2][0] += wA2 * fA0; acc[2][1] += wA2 * fA1; acc[2][2] += wA2 * fA2; acc[2][3] += wA2 * fA3;
    acc[3][0] += wA3 * fA0; acc[3][1] += wA3 * fA1; acc[3][2] += wA3 * fA2; acc[3][3] += wA3 * fA3;
    acc[0][0] += wB0 * fB0; acc[0][1] += wB0 * fB1; acc[0][2] += wB0 * fB2; acc[0][3] += wB0 * fB3;
    acc[1][0] += wB1 * fB0; acc[1][1] += wB1 * fB1; acc[1][2] += wB1 * fB2; acc[1][3] += wB1 * fB3;
    acc[2][0] += wB2 * fB0; acc[2][1] += wB2 * fB1; acc[2][2] += wB2 * fB2; acc[2][3] += wB2 * fB3;
    acc[3][0] += wB3 * fB0; acc[3][1] += wB3 * fB1; acc[3][2] += wB3 * fB2; acc[3][3] += wB3 * fB3;
    wsum[0] += wA0 + wB0; wsum[1] += wA1 + wB1; wsum[2] += wA2 + wB2; wsum[3] += wA3 + wB3;
  }
#pragma unroll
  for (int h = 0; h < 4; ++h) {
#pragma unroll
    for (int c = 0; c < 4; ++c) {
      acc[h][c] += __shfl_xor(acc[h][c], 16, 64);
      acc[h][c] += __shfl_xor(acc[h][c], 32, 64);
    }
    wsum[h] += __shfl_xor(wsum[h], 16, 64);
    wsum[h] += __shfl_xor(wsum[h], 32, 64);
  }
  if (g == 0) {
#pragma unroll
    for (int h = 0; h < 4; ++h) {
      float inv = 1.0f / wsum[h];
      bf16x4 o;
      o[0] = (__bf16)(acc[h][0] * inv); o[1] = (__bf16)(acc[h][1] * inv);
      o[2] = (__bf16)(acc[h][2] * inv); o[3] = (__bf16)(acc[h][3] * inv);
      *(bf16x4*)(aggE + (size_t)d * 256 + h * 64 + p * 4) = o;
    }
  }
}

// ---------- reconstruct x1 (per-head MFMA GEMM + bias + ELU) with fused alpha2 partials ----------
__global__ __launch_bounds__(256) void gemm1p_kernel(const __bf16* __restrict__ aggE,
                                                     const __bf16* __restrict__ W1T,
                                                     const float* __restrict__ b1,
                                                     const float* __restrict__ vs2,
                                                     const float* __restrict__ vd2,
                                                     __bf16* __restrict__ x1,
                                                     float* __restrict__ as2p,
                                                     float* __restrict__ ad2p, int M) {
  __shared__ __bf16 Asl[128 * 72];
  __shared__ __bf16 Bsl[128 * 72];
  int tid = threadIdx.x;
  int h = blockIdx.z;
  int m0 = blockIdx.x * 128;
  int wave = tid >> 6, lane = tid & 63;
  int wm = (wave >> 1) * 64, wn = (wave & 1) * 64;
  int l15 = lane & 15, kg = lane >> 4;
#pragma unroll
  for (int i = 0; i < 4; ++i) {
    int c = tid + i * 256;
    int row = c >> 3, off = (c & 7) * 8;
    bf16x8 va = {};
    int gr = m0 + row;
    if (gr < M) va = *(const bf16x8*)(aggE + (size_t)gr * 256 + h * 64 + off);
    *(bf16x8*)(&Asl[row * 72 + off]) = va;
    bf16x8 vb = *(const bf16x8*)(W1T + ((size_t)h * 128 + row) * 64 + off);
    *(bf16x8*)(&Bsl[row * 72 + off]) = vb;
  }
  __syncthreads();
  f32x4 acc[4][4] = {};
#pragma unroll
  for (int ks = 0; ks < 2; ++ks) {
    bf16x8 af[4], bfr[4];
#pragma unroll
    for (int f = 0; f < 4; ++f) {
      af[f]  = *(const bf16x8*)(&Asl[(wm + f * 16 + l15) * 72 + kg * 8 + ks * 32]);
      bfr[f] = *(const bf16x8*)(&Bsl[(wn + f * 16 + l15) * 72 + kg * 8 + ks * 32]);
    }
#pragma unroll
    for (int i = 0; i < 4; ++i)
#pragma unroll
      for (int j = 0; j < 4; ++j)
        acc[i][j] = __builtin_amdgcn_mfma_f32_16x16x32_bf16(af[i], bfr[j], acc[i][j], 0, 0, 0);
  }
  float bv[4], vsv[4], vdv[4];
#pragma unroll
  for (int j = 0; j < 4; ++j) {
    int col = h * 128 + wn + j * 16 + l15;
    bv[j] = b1[col]; vsv[j] = vs2[col]; vdv[j] = vd2[col];
  }
  int slab = h * 2 + (wn >> 6);
#pragma unroll
  for (int i = 0; i < 4; ++i)
#pragma unroll
    for (int r = 0; r < 4; ++r) {
      int lrow = wm + i * 16 + kg * 4 + r;
      int row = m0 + lrow;
      bool vrow = row < M;
      float ps = 0.f, pd = 0.f;
#pragma unroll
      for (int j = 0; j < 4; ++j) {
        float a = acc[i][j][r] + bv[j];
        a = a > 0.f ? a : __expf(a) - 1.f;   // ELU
        __bf16 xb = (__bf16)a;
        if (vrow) x1[(size_t)row * 512 + h * 128 + wn + j * 16 + l15] = xb;
        float af = (float)xb;
        ps += af * vsv[j];
        pd += af * vdv[j];
      }
      ps += __shfl_xor(ps, 1, 16); ps += __shfl_xor(ps, 2, 16);
      ps += __shfl_xor(ps, 4, 16); ps += __shfl_xor(ps, 8, 16);
      pd += __shfl_xor(pd, 1, 16); pd += __shfl_xor(pd, 2, 16);
      pd += __shfl_xor(pd, 4, 16); pd += __shfl_xor(pd, 8, 16);
      if (l15 == 0 && vrow) {
        as2p[(size_t)slab * M + row] = ps;
        ad2p[(size_t)slab * M + row] = pd;
      }
    }
}

// ---------- merge alpha2 partial slabs ----------
__global__ void merge_alpha2_kernel(const float* __restrict__ as2p, const float* __restrict__ ad2p,
                                    float* __restrict__ as2, float* __restrict__ ad2, int n) {
  int i = blockIdx.x * blockDim.x + threadIdx.x;
  if (i >= n) return;
  float s = 0.f, d = 0.f;
#pragma unroll
  for (int b = 0; b < 8; ++b) {
    s += as2p[(size_t)b * n + i];
    d += ad2p[(size_t)b * n + i];
  }
  as2[i] = s; ad2[i] = d;
}

// ---------- layer-2 denom: advw[d] = {ad2[d], invN / sum_e w_e} ----------
__global__ __launch_bounds__(256) void invw_kernel(
    const int* __restrict__ off, const unsigned* __restrict__ pkD,
    const float* __restrict__ as2, const float* __restrict__ ad2,
    float2* __restrict__ advw, float invN, int n) {
  int d = (blockIdx.x * 256 + threadIdx.x) >> 4;
  int p = threadIdx.x & 15;
  if (d >= n) return;
  float adv = ad2[d];
  int beg = off[d], end = off[d + 1];
  float wsum = 0.f;
  for (int i = beg + p; i < end; i += 16) {
    float l = as2[pkD[i] & 0xFFFF] + adv;
    l = l >= 0.f ? l : NEG_SLOPE * l;
    wsum += __expf(l);
  }
  wsum += __shfl_xor(wsum, 1, 16); wsum += __shfl_xor(wsum, 2, 16);
  wsum += __shfl_xor(wsum, 4, 16); wsum += __shfl_xor(wsum, 8, 16);
  if (p == 0) advw[d] = make_float2(adv, invN / wsum);
}

// ---------- gamma via CSC walk (no atomics) ----------
__global__ __launch_bounds__(256) void gamma_csc_kernel(
    const int* __restrict__ offS, const unsigned* __restrict__ pkS,
    const float* __restrict__ as2, const float2* __restrict__ advw,
    float* __restrict__ gamma, int n) {
  int s = (blockIdx.x * 256 + threadIdx.x) >> 4;
  int p = threadIdx.x & 15;
  if (s >= n) return;
  float as2s = as2[s];
  int beg = offS[s], end = offS[s + 1];
  float gsum = 0.f;
  for (int i = beg + p; i < end; i += 16) {
    float2 av = advw[pkS[i] & 0xFFFF];
    float l = as2s + av.x;
    l = l >= 0.f ? l : NEG_SLOPE * l;
    gsum += __expf(l) * av.y;
  }
  gsum += __shfl_xor(gsum, 1, 16); gsum += __shfl_xor(gsum, 2, 16);
  gsum += __shfl_xor(gsum, 4, 16); gsum += __shfl_xor(gsum, 8, 16);
  if (p == 0) gamma[s] = gsum;
}

// ---------- weighted column sum stage 1 ----------
__global__ __launch_bounds__(256) void colsum1_kernel(const __bf16* __restrict__ x1,
                                                      const float* __restrict__ gamma,
                                                      float* __restrict__ pcol, int n) {
  __shared__ float sc[512];
  int t = threadIdx.x;
  sc[t] = 0.f; sc[t + 256] = 0.f;
  __syncthreads();
  int lane = t & 63, w = t >> 6;
  float acc[8] = {};
  for (int r = blockIdx.x * 4 + w; r < n; r += gridDim.x * 4) {
    float g = gamma[r];
    bf16x8 v = *(const bf16x8*)(x1 + (size_t)r * 512 + lane * 8);
#pragma unroll
    for (int j = 0; j < 8; ++j) acc[j] += g * (float)v[j];
  }
#pragma unroll
  for (int j = 0; j < 8; ++j) atomicAdd(&sc[lane * 8 + j], acc[j]);
  __syncthreads();
  pcol[(size_t)blockIdx.x * 512 + t] = sc[t];
  pcol[(size_t)blockIdx.x * 512 + 256 + t] = sc[t + 256];
}

// stage 2: parallel block-sliced reduction
__global__ __launch_bounds__(256) void colsum2_kernel(const float* __restrict__ pcol,
                                                      float* __restrict__ colsum, int nb) {
  int c = threadIdx.x;
  int b0 = blockIdx.x * 16;
  float a0 = 0.f, a1 = 0.f;
#pragma unroll 4
  for (int b = b0; b < b0 + 16; ++b) {
    if (b < nb) {
      a0 += pcol[(size_t)b * 512 + c];
      a1 += pcol[(size_t)b * 512 + 256 + c];
    }
  }
  atomicAdd(&colsum[c], a0);
  atomicAdd(&colsum[c + 256], a1);
}

// ---------- final matvec: out[c] = colsum . W2[:,c] + b2[c] ----------
__global__ void final_kernel(const float* __restrict__ colsum, const float* __restrict__ W2,
                             const float* __restrict__ b2, float* __restrict__ out) {
  int c = threadIdx.x;  // 256
  int k0 = blockIdx.x * 64;  // 8 blocks x 64 k
  float acc = 0.f;
  for (int k = k0; k < k0 + 64; ++k) acc += colsum[k] * W2[(size_t)k * 256 + c];
  if (blockIdx.x == 0) acc += b2[c];
  atomicAdd(&out[c], acc);
}

__global__ void bcast_kernel(float* __restrict__ dout, int total) {
  int i = blockIdx.x * blockDim.x + threadIdx.x;
  if (i >= 256 && i < total) dout[i] = dout[i & 255];
}

// ---------- host ----------
extern "C" void kernel_launch(void* const* d_in, const int* in_sizes, int n_in,
                              void* d_out, int out_size, void* d_ws, size_t ws_size,
                              hipStream_t stream) {
  const int* ei = (const int*)d_in[0];
  const float* emb = (const float*)d_in[1];
  const float* W1 = (const float*)d_in[2];
  const float* as1w = (const float*)d_in[3];
  const float* ad1w = (const float*)d_in[4];
  const float* b1 = (const float*)d_in[5];
  const float* W2 = (const float*)d_in[6];
  const float* as2w = (const float*)d_in[7];
  const float* ad2w = (const float*)d_in[8];
  const float* b2 = (const float*)d_in[9];
  float* out = (float*)d_out;

  const int E = in_sizes[0] / 2;
  const int N = in_sizes[1] / 64;
  const int NT = E + N;
  const int CS1 = 1024;                 // colsum stage-1 blocks
  const int nblk = (NT + 1023) / 1024;  // sort blocks per section
  const int M = 2 * 256 * nblk;         // hist size
  const int scanBlocks = (M + 1023) / 1024;

  char* ws = (char*)d_ws;
  size_t o = 0;
  auto alloc = [&](size_t bytes) { size_t r = o; o += (bytes + 255) & ~(size_t)255; return r; };
  __bf16* embb  = (__bf16*)(ws + alloc((size_t)N * 64 * 2));
  __bf16* aggE  = (__bf16*)(ws + alloc((size_t)N * 256 * 2));
  __bf16* x1    = (__bf16*)(ws + alloc((size_t)N * 512 * 2));
  __bf16* W1T   = (__bf16*)(ws + alloc((size_t)512 * 64 * 2));
  float* as1    = (float*)(ws + alloc((size_t)N * 4 * 4));
  float* ad1    = (float*)(ws + alloc((size_t)N * 4 * 4));
  float* as2    = (float*)(ws + alloc((size_t)N * 4));
  float* ad2    = (float*)(ws + alloc((size_t)N * 4));
  float* as2p   = (float*)(ws + alloc((size_t)8 * N * 4));
  float* ad2p   = (float*)(ws + alloc((size_t)8 * N * 4));
  float* pcol   = (float*)(ws + alloc((size_t)CS1 * 512 * 4));
  float2* advw  = (float2*)(ws + alloc((size_t)N * 8));
  float* gamma  = (float*)(ws + alloc((size_t)N * 4));
  int* off      = (int*)(ws + alloc((size_t)(N + 1) * 4));
  int* offS     = (int*)(ws + alloc((size_t)(N + 1) * 4));
  unsigned* pkD = (unsigned*)(ws + alloc((size_t)NT * 4));  // (dst<<16)|src, dst-sorted
  unsigned* pkS = (unsigned*)(ws + alloc((size_t)NT * 4));  // (src<<16)|dst, src-sorted
  unsigned* p1buf = (unsigned*)(ws + alloc((size_t)2 * NT * 4));
  int* hist     = (int*)(ws + alloc((size_t)M * 4));
  int* bsum     = (int*)(ws + alloc(512 * 4));
  float4* ew4   = (float4*)(ws + alloc((size_t)NT * 16));
  size_t zbeg = o;
  float* colsum = (float*)(ws + alloc(512 * 4));
  size_t zend = o;
  float* Vs1    = (float*)(ws + alloc(64 * 4 * 4));
  float* Vd1    = (float*)(ws + alloc(64 * 4 * 4));
  float* vs2    = (float*)(ws + alloc(512 * 4));
  float* vd2    = (float*)(ws + alloc(512 * 4));

  hipMemsetAsync(ws + zbeg, 0, zend - zbeg, stream);
  hipMemsetAsync(d_out, 0, (size_t)out_size * 4, stream);

  // merged prep (weights) + radix histogram
  prep_front_kernel<<<131 + 2 * nblk, 256, 0, stream>>>(W1, as1w, ad1w, W2, as2w, ad2w,
                                                        ei, E, NT, nblk,
                                                        Vs1, Vd1, vs2, vd2, W1T, hist);
  int nb = (N + 255) / 256;
  emb_prep_kernel<<<nb, 256, 0, stream>>>(emb, Vs1, Vd1, embb, as1, ad1, N);

  // atomic-free CSR (by dst) + CSC (by src) via MSD radix sort, packed u32
  exscan1_kernel<<<scanBlocks, 1024, 0, stream>>>(hist, bsum, M);
  exscan2_kernel<<<1, 512, 0, stream>>>(bsum, scanBlocks);
  scatter1_kernel<<<2 * nblk, 256, 0, stream>>>(ei, E, NT, nblk, hist, bsum, p1buf);
  sortlow_kernel<<<512, 1024, 0, stream>>>(hist, bsum, p1buf, nblk, NT, pkD, pkS);

  // edge weights (layer 1) + segment bounds, one dispatch
  int ewBlocks = (NT + 255) / 256;
  int bBlocks = (2 * N + 255) / 256;
  post_sort_kernel<<<ewBlocks + bBlocks, 256, 0, stream>>>(pkD, pkS, as1, ad1,
                                                           ew4, off, offS, NT, N, ewBlocks);

  // layer 1
  agg_emb_kernel<<<N / 2, 128, 0, stream>>>(off, pkD, ew4, embb, aggE);
  dim3 g1((N + 127) / 128, 1, 4);
  gemm1p_kernel<<<g1, 256, 0, stream>>>(aggE, W1T, b1, vs2, vd2, x1, as2p, ad2p, N);
  merge_alpha2_kernel<<<nb, 256, 0, stream>>>(as2p, ad2p, as2, ad2, N);

  // layer 2 collapsed
  invw_kernel<<<(N * 16 + 255) / 256, 256, 0, stream>>>(off, pkD, as2, ad2, advw,
                                                        1.0f / (float)N, N);
  gamma_csc_kernel<<<(N * 16 + 255) / 256, 256, 0, stream>>>(offS, pkS, as2, advw, gamma, N);
  colsum1_kernel<<<CS1, 256, 0, stream>>>(x1, gamma, pcol, N);
  colsum2_kernel<<<CS1 / 16, 256, 0, stream>>>(pcol, colsum, CS1);
  final_kernel<<<8, 256, 0, stream>>>(colsum, W2, b2, out);

  if (out_size > 256) {
    bcast_kernel<<<(out_size + 255) / 256, 256, 0, stream>>>(out, out_size);
  }
}